// Round 4
// baseline (143.257 us; speedup 1.0000x reference)
//
#include <hip/hip_runtime.h>
#include <hip/hip_bf16.h>

// Problem constants (from reference)
#define E_TOTAL 300000
#define N_NODES 50000
#define NDIM    128      // node feature dim (bytes per node in i8 table)
#define KDIM    256      // 2*NDIM = GEMM K
#define HDIM    512      // 2*HIDDEN = GEMM N (both MLP branches fused)
#define BN_EPS  1e-5f
#define NTILES  ((E_TOTAL + 63) / 64)   // 4688 tiles of 64 edges
#define NBLK    512                      // 256 tile-lanes x 2 column-halves
#define TLANES  256                      // tile stride (blocks per column-half)
#define NF_BLOCKS 6250                   // 50000*128/4 values / 256 threads
#define LT_MAX  19                       // max tiles per block (ceil(4688/256))
#define A_SCALE 24.0f                    // fixed i8 scale for node feats (clip ~5.3 sigma)

typedef __attribute__((ext_vector_type(4))) int   i32x4;
typedef const __attribute__((address_space(1))) unsigned int* gas1_t;
typedef __attribute__((address_space(3))) unsigned int* las3_t;

__device__ __forceinline__ int q8(float x, float s) {
  float v = fminf(fmaxf(x * s, -127.f), 127.f);
  return (int)rintf(v);
}

// ---- fused prep kernel ----
// blocks [0, NF_BLOCKS): node_feat fp32 -> i8 table (scale A_SCALE)
// blocks [NF_BLOCKS, NF_BLOCKS+32): W1 (BN-folded, roll-fused) -> i8 frag order
//   (operand-symmetric layout, reused as MFMA A-operand), per-column amax scaling.
//   Scales FOLDED: c2i[j] = rint(cj/rv_j) (INT, becomes the MFMA C-init),
//   wp2[j] = 0.5*W2*rv_j, rv_j = amax_b/(127*A_SCALE) > 0.
__global__ void prep_kernel(const float* __restrict__ nf, unsigned char* __restrict__ nfq,
                            const float* __restrict__ W1, const float* __restrict__ b1,
                            const float* __restrict__ gamma, const float* __restrict__ beta,
                            const float* __restrict__ mean, const float* __restrict__ var,
                            const float* __restrict__ W2,
                            unsigned char* __restrict__ Wswz,
                            int* __restrict__ c2i, float* __restrict__ wp2) {
  int b = blockIdx.x;
  int tid = threadIdx.x;
  if (b < NF_BLOCKS) {
    int i = b * 256 + tid;                     // exactly 1.6M float4s
    float4 v = ((const float4*)nf)[i];
    int q0 = q8(v.x, A_SCALE), q1 = q8(v.y, A_SCALE);
    int q2 = q8(v.z, A_SCALE), q3 = q8(v.w, A_SCALE);
    ((unsigned*)nfq)[i] = (q0 & 255) | ((q1 & 255) << 8) | ((q2 & 255) << 16) | ((q3 & 255) << 24);
  } else {
    int ct = b - NF_BLOCKS;                    // 0..31
    __shared__ float amx[16][16];
    __shared__ float sB[16];                   // 127/amax_b per local column
    // pass 1: per-column amax of |W1| (roll is a permutation: same value set)
    {
      int cl = tid >> 4, pt = tid & 15;
      int jj = (ct * 16 + cl) & 255;
      float m = 0.f;
      #pragma unroll
      for (int i = 0; i < 16; i++)
        m = fmaxf(m, fabsf(W1[(pt * 16 + i) * 256 + jj]));
      amx[cl][pt] = m;
    }
    __syncthreads();
    if (tid < 16) {
      int j  = ct * 16 + tid;
      int jj = j & 255;
      float s = gamma[jj] * rsqrtf(var[jj] + BN_EPS);
      float m = 0.f;
      #pragma unroll
      for (int p = 0; p < 16; p++) m = fmaxf(m, amx[tid][p]);
      float amax_b = fmaxf(m * fabsf(s), 1e-20f);
      sB[tid] = 127.f / amax_b;
      float rv = amax_b / (127.f * A_SCALE);
      float cj = b1[jj] * s + beta[jj] - mean[jj] * s;
      float c2 = fminf(fmaxf(cj / rv, -1e9f), 1e9f);
      c2i[j] = (int)rintf(c2);                 // int C-init (<=0.5 unit rounding,
                                               // << i8 quantization noise)
      wp2[j] = 0.5f * W2[jj] * rv;             // fold the 0.5 average + rv
    }
    __syncthreads();
    // pass 2: quantize into frag order (lane: col=ct*16+l16, k=kt*64+quad*16+..)
    {
      int kt   = tid >> 6;                     // 0..3
      int lane = tid & 63;
      int l16  = lane & 15, quad = lane >> 4;
      int col  = ct * 16 + l16;
      int jj   = col & 255;
      int shift = (col >= 256) ? 16 : 0;
      float s  = gamma[jj] * rsqrtf(var[jj] + BN_EPS);
      float sc = sB[l16];
      unsigned o[4];
      #pragma unroll
      for (int d = 0; d < 4; d++) {
        unsigned pk = 0;
        #pragma unroll
        for (int jb = 0; jb < 4; jb++) {
          int k  = kt * 64 + quad * 16 + d * 4 + jb;
          int ks = (k + shift) & 255;
          int q  = q8(W1[ks * 256 + jj] * s, sc);
          pk |= (unsigned)(q & 255) << (8 * jb);
        }
        o[d] = pk;
      }
      *(uint4*)(Wswz + ((size_t)(ct * 4 + kt) * 64 + lane) * 16) = *(const uint4*)o;
    }
  }
}

// ---- main: persistent, 512 threads = 8 waves, 16x16x64 i8 MFMA, TRANSPOSED:
// W = A-operand (M = columns), edges = B-operand (N = edges, DMA-staged in
// B-frag order). COLUMN-SPLIT blocks: block b owns columns [ph*256,ph*256+256),
// ph = b&1; tiles tb = b>>1, stride TLANES.
//
// Round-4 structure: dual-accumulator pair pipeline. Per loop iteration:
//   MFMA(lt)->accA ; MFMA(lt+1)->accB ; epilogue(accA) ; epilogue(accB)
// epilogue(A) is independent of accB's MFMA chain -> scheduler interleaves its
// VALU into accB's MFMA issue gaps (hides ~256cy VALU under ~650cy matrix).
// C-init = c2i (int BN/bias fold) -> epilogue is max_i32+cvt+fmac (3 ops/elem).
// Regs: accA+accB 64 + bq 32 + transients ~25 ~= 120 <= 128 (4 waves/SIMD cap).
// LDS = Ab 64K + idxl 4.75K + partial 8K + c2il/wvl 2K = 80640 <= 81920 -> 2 blk/CU.
__global__ __launch_bounds__(512, 4) void edge_mlp_kernel(
    const unsigned char* __restrict__ nfq, const int* __restrict__ eidx,
    const unsigned char* __restrict__ Wswz, const int* __restrict__ c2i,
    const float* __restrict__ wp2, float* __restrict__ part) {
  __shared__ unsigned char Ab[4][16 * 1024];   // 64 KB: 16 frags x 64 lanes x 16B
  __shared__ unsigned short idxl[LT_MAX * 128];// 4.75 KB (node ids < 65536)
  __shared__ float partial[4][8][64];          // 8 KB, ring by tile&3
  __shared__ int   c2il[256];                  // 1 KB int C-init (this half)
  __shared__ float wvl[256];                   // 1 KB

  const int tid  = threadIdx.x;
  const int w    = tid >> 6;
  const int lane = tid & 63;
  const int l16  = lane & 15;
  const int quad = lane >> 4;
  const int b    = blockIdx.x;
  const int ph   = b & 1;                      // column half
  const int tb   = b >> 1;                     // tile lane
  const int ntl  = (NTILES - tb + TLANES - 1) / TLANES;   // 18 or 19

  // ---- W into registers (once): wave w -> col-tiles ct = ph*16 + w*2 + mt ----
  const i32x4* Wf = (const i32x4*)Wswz;
  i32x4 bq[2][4];
  #pragma unroll
  for (int mt = 0; mt < 2; mt++)
    #pragma unroll
    for (int kt = 0; kt < 4; kt++)
      bq[mt][kt] = Wf[(((ph * 16 + w * 2 + mt) * 4) + kt) * 64 + lane];

  // epilogue consts -> LDS (this half's 256 columns)
  if (tid < 256) c2il[tid] = c2i[ph * 256 + tid];
  else           wvl[tid - 256] = wp2[ph * 256 + tid - 256];

  // ---- preload ALL this block's edge indices into LDS (u16) ----
  for (int g = tid; g < ntl * 128; g += 512) {
    int lt2 = g >> 7, r = g & 127;
    int half = r >> 6;
    int e = (tb + lt2 * TLANES) * 64 + (r & 63);
    if (e >= E_TOTAL) e = E_TOTAL - 1;
    idxl[g] = (unsigned short)eidx[half * E_TOTAL + e];
  }
  __syncthreads();

  // staging role (wave-constant): wave w stages frags f = (w&3)*4 + (w>>2)*2 + i
  const int snt   = w & 3;
  const int shalf = w >> 2;
  const int sfrag0 = snt * 4 + shalf * 2;

  auto stage = [&](int lt2, int slot) {
    int node = idxl[lt2 * 128 + shalf * 64 + snt * 16 + l16];
    const unsigned char* gbase = nfq + (size_t)node * NDIM + quad * 16;
    #pragma unroll
    for (int i = 0; i < 2; i++)
      __builtin_amdgcn_global_load_lds((gas1_t)(gbase + i * 64),
                                       (las3_t)(&Ab[slot][(sfrag0 + i) * 1024]),
                                       16, 0, 0);
  };

  auto combine = [&](int lt2, int le) {
    int e = (tb + lt2 * TLANES) * 64 + le;
    if (e < E_TOTAL) {
      float s = 0.f;
      #pragma unroll
      for (int ww = 0; ww < 8; ww++) s += partial[lt2 & 3][ww][le];
      part[ph * E_TOTAL + e] = s;              // sigmoid kernel sums halves
    }
  };

  // MFMA phase: C-init from c2il, accumulate K=256 (4 kt), single-ef reads.
  auto mfma_tile = [&](int lt2, i32x4 (&acc)[2][4]) {
    i32x4 ci[2];
    #pragma unroll
    for (int mt = 0; mt < 2; mt++)
      ci[mt] = *(const i32x4*)&c2il[w * 32 + mt * 16 + quad * 4];
    #pragma unroll
    for (int mt = 0; mt < 2; mt++)
      #pragma unroll
      for (int nt = 0; nt < 4; nt++)
        acc[mt][nt] = ci[mt];
    const unsigned char* Ap = &Ab[lt2 & 3][lane * 16];
    #pragma unroll
    for (int kt = 0; kt < 4; kt++) {
      #pragma unroll
      for (int nt = 0; nt < 4; nt++) {
        i32x4 ef = *(const i32x4*)(Ap + (nt * 4 + kt) * 1024);
        acc[0][nt] = __builtin_amdgcn_mfma_i32_16x16x64_i8(bq[0][kt], ef, acc[0][nt], 0, 0, 0);
        acc[1][nt] = __builtin_amdgcn_mfma_i32_16x16x64_i8(bq[1][kt], ef, acc[1][nt], 0, 0, 0);
      }
    }
  };

  // epilogue: 3 VALU/elem (max_i32, cvt, fmac); 2 cross-quad shfl stages.
  auto epi_tile = [&](int lt2, i32x4 (&acc)[2][4]) {
    float4 wv0 = *(const float4*)&wvl[w * 32 + 0 * 16 + quad * 4];
    float4 wv1 = *(const float4*)&wvl[w * 32 + 1 * 16 + quad * 4];
    float vnt[4];
    #pragma unroll
    for (int nt = 0; nt < 4; nt++) {
      float v = 0.f;
      int h;
      h = acc[0][nt][0]; v = fmaf((float)(h > 0 ? h : 0), wv0.x, v);
      h = acc[0][nt][1]; v = fmaf((float)(h > 0 ? h : 0), wv0.y, v);
      h = acc[0][nt][2]; v = fmaf((float)(h > 0 ? h : 0), wv0.z, v);
      h = acc[0][nt][3]; v = fmaf((float)(h > 0 ? h : 0), wv0.w, v);
      h = acc[1][nt][0]; v = fmaf((float)(h > 0 ? h : 0), wv1.x, v);
      h = acc[1][nt][1]; v = fmaf((float)(h > 0 ? h : 0), wv1.y, v);
      h = acc[1][nt][2]; v = fmaf((float)(h > 0 ? h : 0), wv1.z, v);
      h = acc[1][nt][3]; v = fmaf((float)(h > 0 ? h : 0), wv1.w, v);
      vnt[nt] = v;
    }
    #pragma unroll
    for (int nt = 0; nt < 4; nt++) vnt[nt] += __shfl_xor(vnt[nt], 16);
    #pragma unroll
    for (int nt = 0; nt < 4; nt++) vnt[nt] += __shfl_xor(vnt[nt], 32);
    if (quad == 0) {
      #pragma unroll
      for (int nt = 0; nt < 4; nt++)
        partial[lt2 & 3][w][nt * 16 + l16] = vnt[nt];
    }
  };

  // ---- prologue: stage tiles 0,1 ----
  stage(0, 0);
  if (1 < ntl) stage(1, 1);

  // ---- main loop: one barrier per PAIR of tiles; dual-acc pipeline ----
  for (int lt = 0; lt < ntl; lt += 2) {
    __syncthreads();   // drains own DMAs (issued a full pair ago), syncs partial ring

    int s2 = lt + 2, s3 = lt + 3;
    if (s2 < ntl) stage(s2, s2 & 3);
    if (s3 < ntl) stage(s3, s3 & 3);

    i32x4 accA[2][4], accB[2][4];
    bool haveB = (lt + 1 < ntl);
    mfma_tile(lt, accA);
    if (haveB) mfma_tile(lt + 1, accB);

    if (lt >= 2) {
      if (tid < 64)       combine(lt - 2, tid);
      else if (tid < 128) combine(lt - 1, tid - 64);
    }

    epi_tile(lt, accA);                 // interleaves under accB's MFMAs
    if (haveB) epi_tile(lt + 1, accB);
  }

  // ---- tail: combine the last pair ----
  __syncthreads();
  if ((ntl & 1) == 0) {
    if (tid < 64)       combine(ntl - 2, tid);
    else if (tid < 128) combine(ntl - 1, tid - 64);
  } else {
    if (tid < 64)       combine(ntl - 1, tid);
  }
}

// ---- final: out = sigmoid(part0 + part1 + b2), vectorized float4 ----
__global__ void sigmoid_kernel(const float* __restrict__ part,
                               const float* __restrict__ b2,
                               float* __restrict__ out) {
  int i = blockIdx.x * 256 + threadIdx.x;      // float4 index, 75000 total
  if (i < E_TOTAL / 4) {
    float4 a = ((const float4*)part)[i];
    float4 c = ((const float4*)(part + E_TOTAL))[i];
    float bb = b2[0];
    float4 o;
    o.x = 1.0f / (1.0f + __expf(-(a.x + c.x + bb)));
    o.y = 1.0f / (1.0f + __expf(-(a.y + c.y + bb)));
    o.z = 1.0f / (1.0f + __expf(-(a.z + c.z + bb)));
    o.w = 1.0f / (1.0f + __expf(-(a.w + c.w + bb)));
    ((float4*)out)[i] = o;
  }
}

extern "C" void kernel_launch(void* const* d_in, const int* in_sizes, int n_in,
                              void* d_out, int out_size, void* d_ws, size_t ws_size,
                              hipStream_t stream) {
  const float* node_feat = (const float*)d_in[0];
  const int*   eidx      = (const int*)d_in[1];
  const float* W1        = (const float*)d_in[2];
  const float* b1        = (const float*)d_in[3];
  const float* gamma     = (const float*)d_in[4];
  const float* beta      = (const float*)d_in[5];
  const float* mean      = (const float*)d_in[6];
  const float* var       = (const float*)d_in[7];
  const float* W2        = (const float*)d_in[8];
  const float* b2        = (const float*)d_in[9];
  float* out = (float*)d_out;

  // Workspace: Wswz i8[512*256] (128KB) | c2i i32[512] | wp2 f32[512]
  //          | nfq i8[50000*128] (6.4MB) | part f32[2*300000] (2.4MB)
  unsigned char* Wswz = (unsigned char*)d_ws;
  int*   c2i = (int*)((char*)d_ws + (size_t)HDIM * KDIM);
  float* wp2 = (float*)(c2i + HDIM);
  unsigned char* nfq = (unsigned char*)(wp2 + HDIM);
  float* part = (float*)(nfq + (size_t)N_NODES * NDIM);

  prep_kernel<<<NF_BLOCKS + 32, 256, 0, stream>>>(node_feat, nfq, W1, b1, gamma, beta,
                                                  mean, var, W2, Wswz, c2i, wp2);

  edge_mlp_kernel<<<NBLK, 512, 0, stream>>>(nfq, eidx, Wswz, c2i, wp2, part);

  sigmoid_kernel<<<(E_TOTAL / 4 + 255) / 256, 256, 0, stream>>>(part, b2, out);
}

// Round 5
// 133.964 us; speedup vs baseline: 1.0694x; 1.0694x over previous
//
#include <hip/hip_runtime.h>
#include <hip/hip_bf16.h>

// Problem constants (from reference)
#define E_TOTAL 300000
#define N_NODES 50000
#define NDIM    128      // node feature dim (bytes per node in i8 table)
#define KDIM    256      // 2*NDIM = GEMM K
#define HDIM    512      // 2*HIDDEN = GEMM N (both MLP branches fused)
#define BN_EPS  1e-5f
#define NTILES  ((E_TOTAL + 63) / 64)   // 4688 tiles of 64 edges
#define NBLK    512                      // 256 tile-lanes x 2 column-halves
#define TLANES  256                      // tile stride (blocks per column-half)
#define NF_BLOCKS 6250                   // 50000*128/4 values / 256 threads
#define LT_MAX  19                       // max tiles per block (ceil(4688/256))
#define A_SCALE 24.0f                    // fixed i8 scale for node feats (clip ~5.3 sigma)

typedef __attribute__((ext_vector_type(4))) int   i32x4;
typedef const __attribute__((address_space(1))) unsigned int* gas1_t;
typedef __attribute__((address_space(3))) unsigned int* las3_t;

__device__ __forceinline__ int q8(float x, float s) {
  float v = fminf(fmaxf(x * s, -127.f), 127.f);
  return (int)rintf(v);
}

// ---- fused prep kernel ----
// blocks [0, NF_BLOCKS): node_feat fp32 -> i8 table (scale A_SCALE)
// blocks [NF_BLOCKS, NF_BLOCKS+32): W1 (BN-folded, roll-fused) -> i8 frag order
//   (operand-symmetric layout, reused as MFMA A-operand), per-column amax scaling.
//   Scales FOLDED: c2i[j] = rint(cj/rv_j) (INT, becomes the MFMA C-init),
//   wp2[j] = 0.5*W2*rv_j, rv_j = amax_b/(127*A_SCALE) > 0.
__global__ void prep_kernel(const float* __restrict__ nf, unsigned char* __restrict__ nfq,
                            const float* __restrict__ W1, const float* __restrict__ b1,
                            const float* __restrict__ gamma, const float* __restrict__ beta,
                            const float* __restrict__ mean, const float* __restrict__ var,
                            const float* __restrict__ W2,
                            unsigned char* __restrict__ Wswz,
                            int* __restrict__ c2i, float* __restrict__ wp2) {
  int b = blockIdx.x;
  int tid = threadIdx.x;
  if (b < NF_BLOCKS) {
    int i = b * 256 + tid;                     // exactly 1.6M float4s
    float4 v = ((const float4*)nf)[i];
    int q0 = q8(v.x, A_SCALE), q1 = q8(v.y, A_SCALE);
    int q2 = q8(v.z, A_SCALE), q3 = q8(v.w, A_SCALE);
    ((unsigned*)nfq)[i] = (q0 & 255) | ((q1 & 255) << 8) | ((q2 & 255) << 16) | ((q3 & 255) << 24);
  } else {
    int ct = b - NF_BLOCKS;                    // 0..31
    __shared__ float amx[16][16];
    __shared__ float sB[16];                   // 127/amax_b per local column
    // pass 1: per-column amax of |W1| (roll is a permutation: same value set)
    {
      int cl = tid >> 4, pt = tid & 15;
      int jj = (ct * 16 + cl) & 255;
      float m = 0.f;
      #pragma unroll
      for (int i = 0; i < 16; i++)
        m = fmaxf(m, fabsf(W1[(pt * 16 + i) * 256 + jj]));
      amx[cl][pt] = m;
    }
    __syncthreads();
    if (tid < 16) {
      int j  = ct * 16 + tid;
      int jj = j & 255;
      float s = gamma[jj] * rsqrtf(var[jj] + BN_EPS);
      float m = 0.f;
      #pragma unroll
      for (int p = 0; p < 16; p++) m = fmaxf(m, amx[tid][p]);
      float amax_b = fmaxf(m * fabsf(s), 1e-20f);
      sB[tid] = 127.f / amax_b;
      float rv = amax_b / (127.f * A_SCALE);
      float cj = b1[jj] * s + beta[jj] - mean[jj] * s;
      float c2 = fminf(fmaxf(cj / rv, -1e9f), 1e9f);
      c2i[j] = (int)rintf(c2);                 // int C-init (<=0.5 unit rounding,
                                               // << i8 quantization noise)
      wp2[j] = 0.5f * W2[jj] * rv;             // fold the 0.5 average + rv
    }
    __syncthreads();
    // pass 2: quantize into frag order (lane: col=ct*16+l16, k=kt*64+quad*16+..)
    {
      int kt   = tid >> 6;                     // 0..3
      int lane = tid & 63;
      int l16  = lane & 15, quad = lane >> 4;
      int col  = ct * 16 + l16;
      int jj   = col & 255;
      int shift = (col >= 256) ? 16 : 0;
      float s  = gamma[jj] * rsqrtf(var[jj] + BN_EPS);
      float sc = sB[l16];
      unsigned o[4];
      #pragma unroll
      for (int d = 0; d < 4; d++) {
        unsigned pk = 0;
        #pragma unroll
        for (int jb = 0; jb < 4; jb++) {
          int k  = kt * 64 + quad * 16 + d * 4 + jb;
          int ks = (k + shift) & 255;
          int q  = q8(W1[ks * 256 + jj] * s, sc);
          pk |= (unsigned)(q & 255) << (8 * jb);
        }
        o[d] = pk;
      }
      *(uint4*)(Wswz + ((size_t)(ct * 4 + kt) * 64 + lane) * 16) = *(const uint4*)o;
    }
  }
}

// ---- main: persistent, 512 threads = 8 waves, 16x16x64 i8 MFMA, TRANSPOSED:
// W = A-operand (M = columns), edges = B-operand (N = edges, DMA-staged in
// B-frag order). COLUMN-SPLIT blocks: block b owns columns [ph*256,ph*256+256),
// ph = b&1; tiles tb = b>>1, stride TLANES.
//
// Round-5 structure: per-nt staggered epilogue. nt is the OUTER loop of the
// tile; the 8-MFMA chain of subtile nt runs while the epilogue (max_i32 + cvt
// + fmac, int C-init already folded) of subtile nt-1 issues on the VALU.
// Live acc = current(8) + previous(8) = 16 regs — the overlap costs no
// register high-water (round-4 lesson: 64-reg dual-acc spilled).
// Regs ~85 <= 128 cap -> honest 4 waves/SIMD; LDS 80640 <= 81920 -> 2 blk/CU.
__global__ __launch_bounds__(512, 4) void edge_mlp_kernel(
    const unsigned char* __restrict__ nfq, const int* __restrict__ eidx,
    const unsigned char* __restrict__ Wswz, const int* __restrict__ c2i,
    const float* __restrict__ wp2, float* __restrict__ part) {
  __shared__ unsigned char Ab[4][16 * 1024];   // 64 KB: 16 frags x 64 lanes x 16B
  __shared__ unsigned short idxl[LT_MAX * 128];// 4.75 KB (node ids < 65536)
  __shared__ float partial[4][8][64];          // 8 KB, ring by tile&3
  __shared__ int   c2il[256];                  // 1 KB int C-init (this half)
  __shared__ float wvl[256];                   // 1 KB

  const int tid  = threadIdx.x;
  const int w    = tid >> 6;
  const int lane = tid & 63;
  const int l16  = lane & 15;
  const int quad = lane >> 4;
  const int b    = blockIdx.x;
  const int ph   = b & 1;                      // column half
  const int tb   = b >> 1;                     // tile lane
  const int ntl  = (NTILES - tb + TLANES - 1) / TLANES;   // 18 or 19

  // ---- W into registers (once): wave w -> col-tiles ct = ph*16 + w*2 + mt ----
  const i32x4* Wf = (const i32x4*)Wswz;
  i32x4 bq[2][4];
  #pragma unroll
  for (int mt = 0; mt < 2; mt++)
    #pragma unroll
    for (int kt = 0; kt < 4; kt++)
      bq[mt][kt] = Wf[(((ph * 16 + w * 2 + mt) * 4) + kt) * 64 + lane];

  // epilogue consts -> LDS (this half's 256 columns)
  if (tid < 256) c2il[tid] = c2i[ph * 256 + tid];
  else           wvl[tid - 256] = wp2[ph * 256 + tid - 256];

  // ---- preload ALL this block's edge indices into LDS (u16) ----
  for (int g = tid; g < ntl * 128; g += 512) {
    int lt2 = g >> 7, r = g & 127;
    int half = r >> 6;
    int e = (tb + lt2 * TLANES) * 64 + (r & 63);
    if (e >= E_TOTAL) e = E_TOTAL - 1;
    idxl[g] = (unsigned short)eidx[half * E_TOTAL + e];
  }
  __syncthreads();

  // staging role (wave-constant): wave w stages frags f = (w&3)*4 + (w>>2)*2 + i
  const int snt   = w & 3;
  const int shalf = w >> 2;
  const int sfrag0 = snt * 4 + shalf * 2;

  auto stage = [&](int lt2, int slot) {
    int node = idxl[lt2 * 128 + shalf * 64 + snt * 16 + l16];
    const unsigned char* gbase = nfq + (size_t)node * NDIM + quad * 16;
    #pragma unroll
    for (int i = 0; i < 2; i++)
      __builtin_amdgcn_global_load_lds((gas1_t)(gbase + i * 64),
                                       (las3_t)(&Ab[slot][(sfrag0 + i) * 1024]),
                                       16, 0, 0);
  };

  auto combine = [&](int lt2, int le) {
    int e = (tb + lt2 * TLANES) * 64 + le;
    if (e < E_TOTAL) {
      float s = 0.f;
      #pragma unroll
      for (int ww = 0; ww < 8; ww++) s += partial[lt2 & 3][ww][le];
      part[ph * E_TOTAL + e] = s;              // sigmoid kernel sums halves
    }
  };

  auto compute_tile = [&](int lt2) {
    const unsigned char* Ap = &Ab[lt2 & 3][lane * 16];
    i32x4 ci0 = *(const i32x4*)&c2il[w * 32 + quad * 4];
    i32x4 ci1 = *(const i32x4*)&c2il[w * 32 + 16 + quad * 4];
    float4 wv0 = *(const float4*)&wvl[w * 32 + quad * 4];
    float4 wv1 = *(const float4*)&wvl[w * 32 + 16 + quad * 4];

    auto epi8 = [&](const i32x4& x0, const i32x4& x1) -> float {
      float v = 0.f; int h;
      h = x0[0]; v = fmaf((float)(h > 0 ? h : 0), wv0.x, v);
      h = x0[1]; v = fmaf((float)(h > 0 ? h : 0), wv0.y, v);
      h = x0[2]; v = fmaf((float)(h > 0 ? h : 0), wv0.z, v);
      h = x0[3]; v = fmaf((float)(h > 0 ? h : 0), wv0.w, v);
      h = x1[0]; v = fmaf((float)(h > 0 ? h : 0), wv1.x, v);
      h = x1[1]; v = fmaf((float)(h > 0 ? h : 0), wv1.y, v);
      h = x1[2]; v = fmaf((float)(h > 0 ? h : 0), wv1.z, v);
      h = x1[3]; v = fmaf((float)(h > 0 ? h : 0), wv1.w, v);
      return v;
    };

    float vnt[4];
    i32x4 pa0, pa1;                     // previous subtile's acc (8 live regs)
    #pragma unroll
    for (int nt = 0; nt < 4; nt++) {
      i32x4 a0 = ci0, a1 = ci1;
      #pragma unroll
      for (int kt = 0; kt < 4; kt++) {
        i32x4 ef = *(const i32x4*)(Ap + (nt * 4 + kt) * 1024);
        a0 = __builtin_amdgcn_mfma_i32_16x16x64_i8(bq[0][kt], ef, a0, 0, 0, 0);
        a1 = __builtin_amdgcn_mfma_i32_16x16x64_i8(bq[1][kt], ef, a1, 0, 0, 0);
      }
      // epilogue of nt-1 issues on VALU while nt's MFMA chain is in flight
      if (nt > 0) vnt[nt - 1] = epi8(pa0, pa1);
      pa0 = a0; pa1 = a1;
    }
    vnt[3] = epi8(pa0, pa1);

    #pragma unroll
    for (int nt = 0; nt < 4; nt++) vnt[nt] += __shfl_xor(vnt[nt], 16);
    #pragma unroll
    for (int nt = 0; nt < 4; nt++) vnt[nt] += __shfl_xor(vnt[nt], 32);
    if (quad == 0) {
      #pragma unroll
      for (int nt = 0; nt < 4; nt++)
        partial[lt2 & 3][w][nt * 16 + l16] = vnt[nt];
    }
  };

  // ---- prologue: stage tiles 0,1 ----
  stage(0, 0);
  if (1 < ntl) stage(1, 1);

  // ---- main loop: one barrier per PAIR of tiles ----
  for (int lt = 0; lt < ntl; lt += 2) {
    __syncthreads();   // drains own DMAs (issued a full pair ago), syncs partial ring

    int s2 = lt + 2, s3 = lt + 3;
    if (s2 < ntl) stage(s2, s2 & 3);
    if (s3 < ntl) stage(s3, s3 & 3);

    if (lt >= 2) {
      if (tid < 64)       combine(lt - 2, tid);
      else if (tid < 128) combine(lt - 1, tid - 64);
    }

    compute_tile(lt);
    if (lt + 1 < ntl) compute_tile(lt + 1);
  }

  // ---- tail: combine the last pair ----
  __syncthreads();
  if ((ntl & 1) == 0) {
    if (tid < 64)       combine(ntl - 2, tid);
    else if (tid < 128) combine(ntl - 1, tid - 64);
  } else {
    if (tid < 64)       combine(ntl - 1, tid);
  }
}

// ---- final: out = sigmoid(part0 + part1 + b2), vectorized float4 ----
__global__ void sigmoid_kernel(const float* __restrict__ part,
                               const float* __restrict__ b2,
                               float* __restrict__ out) {
  int i = blockIdx.x * 256 + threadIdx.x;      // float4 index, 75000 total
  if (i < E_TOTAL / 4) {
    float4 a = ((const float4*)part)[i];
    float4 c = ((const float4*)(part + E_TOTAL))[i];
    float bb = b2[0];
    float4 o;
    o.x = 1.0f / (1.0f + __expf(-(a.x + c.x + bb)));
    o.y = 1.0f / (1.0f + __expf(-(a.y + c.y + bb)));
    o.z = 1.0f / (1.0f + __expf(-(a.z + c.z + bb)));
    o.w = 1.0f / (1.0f + __expf(-(a.w + c.w + bb)));
    ((float4*)out)[i] = o;
  }
}

extern "C" void kernel_launch(void* const* d_in, const int* in_sizes, int n_in,
                              void* d_out, int out_size, void* d_ws, size_t ws_size,
                              hipStream_t stream) {
  const float* node_feat = (const float*)d_in[0];
  const int*   eidx      = (const int*)d_in[1];
  const float* W1        = (const float*)d_in[2];
  const float* b1        = (const float*)d_in[3];
  const float* gamma     = (const float*)d_in[4];
  const float* beta      = (const float*)d_in[5];
  const float* mean      = (const float*)d_in[6];
  const float* var       = (const float*)d_in[7];
  const float* W2        = (const float*)d_in[8];
  const float* b2        = (const float*)d_in[9];
  float* out = (float*)d_out;

  // Workspace: Wswz i8[512*256] (128KB) | c2i i32[512] | wp2 f32[512]
  //          | nfq i8[50000*128] (6.4MB) | part f32[2*300000] (2.4MB)
  unsigned char* Wswz = (unsigned char*)d_ws;
  int*   c2i = (int*)((char*)d_ws + (size_t)HDIM * KDIM);
  float* wp2 = (float*)(c2i + HDIM);
  unsigned char* nfq = (unsigned char*)(wp2 + HDIM);
  float* part = (float*)(nfq + (size_t)N_NODES * NDIM);

  prep_kernel<<<NF_BLOCKS + 32, 256, 0, stream>>>(node_feat, nfq, W1, b1, gamma, beta,
                                                  mean, var, W2, Wswz, c2i, wp2);

  edge_mlp_kernel<<<NBLK, 512, 0, stream>>>(nfq, eidx, Wswz, c2i, wp2, part);

  sigmoid_kernel<<<(E_TOTAL / 4 + 255) / 256, 256, 0, stream>>>(part, b2, out);
}